// Round 1
// baseline (1006.922 us; speedup 1.0000x reference)
//
#include <hip/hip_runtime.h>
#include <cstdint>

// Problem constants (N=8192 nodes, K=64 neighbors incl. self, F=128 features)
#define N_NODES 8192
#define K_NB    64
#define F_DIM   128
#define SAMP_W  (2 * F_DIM + 1)          // 257 floats per sample row
#define ROWS_PER_BLK 64                  // adj row-block size
#define NBLK (N_NODES / ROWS_PER_BLK)    // 128 row blocks
#define CW   2048                        // column chunk width for phase 3
#define NCHUNK (N_NODES / CW)            // 4 chunks

// Pack (ordinal, value): u64 atomicMax compares ordinal first (high word).
// ordinal = r*K + j + 1 (0 = "unset/carry"), unique -> value bits never decide.
static __device__ __forceinline__ unsigned long long pack_uv(unsigned int ord, float v) {
    return ((unsigned long long)ord << 32) | (unsigned long long)__float_as_uint(v);
}
static __device__ __forceinline__ float unpack_v(unsigned long long p) {
    return __uint_as_float((unsigned int)(p & 0xffffffffULL));
}

// ---------------------------------------------------------------------------
// samples: row (i*K + j) = [ emb[i] (128) | emb[c] (128) | sw[c] (1) ]
// One WG of 256 threads per node i; 64 rows of 1028 B each, coalesced.
// emb_in is 4 MB -> gather reads are cache hits; kernel is write-BW bound.
// ---------------------------------------------------------------------------
__global__ __launch_bounds__(256) void samples_kernel(
    const float* __restrict__ emb, const float* __restrict__ sw,
    const int* __restrict__ idx, float* __restrict__ out)
{
    const int i = blockIdx.x;
    const int t = threadIdx.x;
    float nd = 0.0f;
    if (t < F_DIM) nd = emb[i * F_DIM + t];           // node vec, reused K times
    const int rowbase = i * (K_NB * SAMP_W);          // < 2^27, int-safe
    for (int j = 0; j < K_NB; ++j) {
        const int c = (j < K_NB - 1) ? idx[i * (K_NB - 1) + j] : i;  // self last
        const int base = rowbase + j * SAMP_W;
        if (t < F_DIM) {
            out[base + t] = nd;
            if (t == 0) out[base + 2 * F_DIM] = sw[c];
        } else {
            out[base + t] = emb[c * F_DIM + (t - F_DIM)];  // coalesced 512B
        }
    }
}

// ---------------------------------------------------------------------------
// P1: per row-block b, per column c: packed max-ordinal update (0 if none).
// LDS line of 8192 u64 (64 KB). 4096 updates per block via atomicMax.
// ---------------------------------------------------------------------------
__global__ __launch_bounds__(256) void p1_kernel(
    const int* __restrict__ idx, const float* __restrict__ edge,
    unsigned long long* __restrict__ S)
{
    __shared__ unsigned long long line[N_NODES];      // 64 KB
    const int b = blockIdx.x;
    const int t = threadIdx.x;
    for (int k = t; k < N_NODES; k += 256) line[k] = 0ULL;
    __syncthreads();
    for (int u = t; u < ROWS_PER_BLK * K_NB; u += 256) {
        const int r = b * ROWS_PER_BLK + (u >> 6);
        const int j = u & 63;
        const int c = (j < K_NB - 1) ? idx[r * (K_NB - 1) + j] : r;
        const float v = edge[r * K_NB + j];
        atomicMax(&line[c], pack_uv((unsigned)(r * K_NB + j + 1), v));
    }
    __syncthreads();
    for (int k = t; k < N_NODES; k += 256) S[b * N_NODES + k] = line[k];
}

// ---------------------------------------------------------------------------
// P2: per column, forward scan over block summaries -> carry-in value per
// (block, column). Block-b summary, if set (nonzero), always has a larger
// ordinal than anything earlier, so the fold is just "take if nonzero".
// ---------------------------------------------------------------------------
__global__ __launch_bounds__(256) void p2_kernel(
    const unsigned long long* __restrict__ S, float* __restrict__ carry)
{
    const int c = blockIdx.x * 256 + threadIdx.x;     // 8192 threads
    unsigned long long run = 0ULL;                    // value 0.0f initially
    for (int b = 0; b < NBLK; ++b) {
        carry[b * N_NODES + c] = unpack_v(run);       // carry = state BEFORE block b
        const unsigned long long s = S[b * N_NODES + c];
        if (s != 0ULL) run = s;
    }
}

// ---------------------------------------------------------------------------
// P3: one WG per (row-block, column-chunk). LDS line (2048 u64 = 16 KB)
// initialized from carry; replay the 64 rows in order: apply the row's <=64
// updates (packed atomicMax handles in-row duplicates + ordering), then
// stream the line to adj[r][chunk] coalesced.
// ---------------------------------------------------------------------------
__global__ __launch_bounds__(256) void p3_kernel(
    const int* __restrict__ idx, const float* __restrict__ edge,
    const float* __restrict__ carry, float* __restrict__ adj)
{
    __shared__ unsigned long long line[CW];           // 16 KB
    const int b  = blockIdx.x;                        // row block
    const int c0 = blockIdx.y * CW;                   // chunk base column
    const int t  = threadIdx.x;
    for (int k = t; k < CW; k += 256)
        line[k] = pack_uv(0u, carry[b * N_NODES + c0 + k]);
    __syncthreads();
    for (int rr = 0; rr < ROWS_PER_BLK; ++rr) {
        const int r = b * ROWS_PER_BLK + rr;
        if (t < K_NB) {
            const int j = t;
            const int c = (j < K_NB - 1) ? idx[r * (K_NB - 1) + j] : r;
            const unsigned int cc = (unsigned)(c - c0);
            if (cc < (unsigned)CW) {
                const float v = edge[r * K_NB + j];
                atomicMax(&line[cc], pack_uv((unsigned)(r * K_NB + j + 1), v));
            }
        }
        __syncthreads();
        const int rowbase = r * N_NODES + c0;         // < 2^27, int-safe
        for (int k = t; k < CW; k += 256)
            adj[rowbase + k] = unpack_v(line[k]);     // coalesced 4B/lane
        __syncthreads();
    }
}

// ---------------------------------------------------------------------------
// Launch. d_out = [samples (134,742,016 f32) | adj (67,108,864 f32)].
// Scratch (S: 8 MB, carry: 4 MB) lives at the FRONT of the samples region;
// samples_kernel runs LAST and overwrites it (stream-ordered, graph-safe) so
// we never depend on ws_size.
// ---------------------------------------------------------------------------
extern "C" void kernel_launch(void* const* d_in, const int* in_sizes, int n_in,
                              void* d_out, int out_size, void* d_ws, size_t ws_size,
                              hipStream_t stream)
{
    const float* emb  = (const float*)d_in[0];
    const float* sw   = (const float*)d_in[1];
    const int*   idx  = (const int*)d_in[2];
    const float* edge = (const float*)d_in[3];

    float* out      = (float*)d_out;
    float* samples  = out;
    float* adj      = out + (size_t)N_NODES * K_NB * SAMP_W;

    unsigned long long* S = (unsigned long long*)d_out;                  // 8 MB
    float* carry = (float*)((char*)d_out + (size_t)NBLK * N_NODES * 8);  // 4 MB

    p1_kernel<<<NBLK, 256, 0, stream>>>(idx, edge, S);
    p2_kernel<<<N_NODES / 256, 256, 0, stream>>>(S, carry);
    p3_kernel<<<dim3(NBLK, NCHUNK), 256, 0, stream>>>(idx, edge, carry, adj);
    samples_kernel<<<N_NODES, 256, 0, stream>>>(emb, sw, idx, samples);
}